// Round 1
// baseline (195.941 us; speedup 1.0000x reference)
//
#include <hip/hip_runtime.h>
#include <hip/hip_bf16.h>

#define DD 32
#define HH 32
#define WW 32
#define NN 32768
#define BB 2
#define CF 256
#define CC 21
#define FD 64
#define KK 19
#define BKP 32

// 19 stencil offsets with |dx|+|dy|+|dz| <= 2 (order irrelevant: softmax+sum over k)
__device__ const int OFF[19][3] = {
    {-1,-1, 0}, {-1, 0,-1}, {-1, 0, 0}, {-1, 0, 1}, {-1, 1, 0},
    { 0,-1,-1}, { 0,-1, 0}, { 0,-1, 1}, { 0, 0,-1}, { 0, 0, 0},
    { 0, 0, 1}, { 0, 1,-1}, { 0, 1, 0}, { 0, 1, 1},
    { 1,-1, 0}, { 1, 0,-1}, { 1, 0, 0}, { 1, 0, 1}, { 1, 1, 0}
};

// ---------------- Kernel 1: projection GEMM ----------------
// C[b,n,j] = sum_c f[b,c,n] * Wcat[c,j] + bias[j],  j in [0,128): 0-63 theta, 64-127 phi
// tile: 128 rows (n) x 128 cols (j), BK=32, 256 threads, 8x8 micro-tile
__global__ __launch_bounds__(256) void proj_kernel(
    const float* __restrict__ f,
    const float* __restrict__ thw, const float* __restrict__ thb,
    const float* __restrict__ phw, const float* __restrict__ phb,
    float* __restrict__ theta, float* __restrict__ phi)
{
    __shared__ __align__(16) float As[BKP][128];  // [kk][m]
    __shared__ __align__(16) float Bs[BKP][128];  // [kk][j]
    int blk = blockIdx.x;
    int b = blk >> 8;                 // 256 blocks per batch
    int n0 = (blk & 255) * 128;
    int tid = threadIdx.x;
    int tm = tid >> 4;                // 0..15
    int tj = tid & 15;                // 0..15
    int m0 = tm * 8, j0 = tj * 8;

    float bias[8];
#pragma unroll
    for (int jj = 0; jj < 8; ++jj)
        bias[jj] = (j0 + jj < 64) ? thb[j0 + jj] : phb[j0 + jj - 64];

    float acc[8][8];
#pragma unroll
    for (int r = 0; r < 8; ++r)
#pragma unroll
        for (int jj = 0; jj < 8; ++jj) acc[r][jj] = 0.f;

    const float* fb = f + (size_t)b * CF * NN;
    int lm = (tid & 31) * 4;          // 0..124
    int lk = tid >> 5;                // 0..7

    for (int k0 = 0; k0 < CF; k0 += BKP) {
#pragma unroll
        for (int i = 0; i < 4; ++i) {
            int kk = lk + i * 8;
            float4 av = *(const float4*)(fb + (size_t)(k0 + kk) * NN + n0 + lm);
            *(float4*)&As[kk][lm] = av;
            float4 wv;
            if (lm < 64) wv = *(const float4*)(thw + (k0 + kk) * 64 + lm);
            else         wv = *(const float4*)(phw + (k0 + kk) * 64 + (lm - 64));
            *(float4*)&Bs[kk][lm] = wv;
        }
        __syncthreads();
#pragma unroll
        for (int kk = 0; kk < BKP; ++kk) {
            float a[8], bb[8];
            *(float4*)&a[0]  = *(float4*)&As[kk][m0];
            *(float4*)&a[4]  = *(float4*)&As[kk][m0 + 4];
            *(float4*)&bb[0] = *(float4*)&Bs[kk][j0];
            *(float4*)&bb[4] = *(float4*)&Bs[kk][j0 + 4];
#pragma unroll
            for (int r = 0; r < 8; ++r)
#pragma unroll
                for (int jj = 0; jj < 8; ++jj) acc[r][jj] += a[r] * bb[jj];
        }
        __syncthreads();
    }

#pragma unroll
    for (int r = 0; r < 8; ++r) {
        int n = n0 + m0 + r;
        float out[8];
#pragma unroll
        for (int jj = 0; jj < 8; ++jj) out[jj] = acc[r][jj] + bias[jj];
        if (j0 < 64) {
            *(float4*)(theta + ((size_t)b * NN + n) * 64 + j0)     = *(float4*)&out[0];
            *(float4*)(theta + ((size_t)b * NN + n) * 64 + j0 + 4) = *(float4*)&out[4];
        } else {
            *(float4*)(phi + ((size_t)b * NN + n) * 64 + (j0 - 64))     = *(float4*)&out[0];
            *(float4*)(phi + ((size_t)b * NN + n) * 64 + (j0 - 64) + 4) = *(float4*)&out[4];
        }
    }
}

// ---------------- Kernel 2: geo projection ----------------
// pe computed analytically; g_theta/g_phi = pe @ W + b.  4 nodes / block, 64 j-threads per node.
__global__ __launch_bounds__(256) void geo_kernel(
    const float* __restrict__ gtw, const float* __restrict__ gtb,
    const float* __restrict__ gpw, const float* __restrict__ gpb,
    float* __restrict__ gth, float* __restrict__ gph)
{
    __shared__ float pe_s[4][48];
    int tid = threadIdx.x;
    int n_base = blockIdx.x * 4;
    if (tid < 192) {
        int node = tid / 48, p = tid % 48;
        int n = n_base + node;
        int d = n >> 10, h = (n >> 5) & 31, w = n & 31;
        int a = p / 16, rem = p % 16, i = rem >> 1, sc = rem & 1;
        float coord = (a == 0) ? (float)d : (a == 1) ? (float)h : (float)w;
        // div = (1e-4)^(i/8)
        float div = expf(-9.210340371976184f * (float)i * 0.125f);
        float ang = coord * div;
        pe_s[node][p] = sc ? cosf(ang) : sinf(ang);
    }
    __syncthreads();
    int node = tid >> 6, j = tid & 63;
    int n = n_base + node;
    float at = gtb[j], ap = gpb[j];
#pragma unroll
    for (int p = 0; p < 48; ++p) {
        float pv = pe_s[node][p];
        at += pv * gtw[p * 64 + j];
        ap += pv * gpw[p * 64 + j];
    }
    gth[(size_t)n * 64 + j] = at;
    gph[(size_t)n * 64 + j] = ap;
}

// ---------------- Kernel 3: scores + masked softmax ----------------
// one wave per (b,n); lane = feature dim; butterfly-reduced dot per neighbor.
__global__ __launch_bounds__(256) void score_kernel(
    const float* __restrict__ theta, const float* __restrict__ phi,
    const float* __restrict__ gth, const float* __restrict__ gph,
    float* __restrict__ wgt)
{
    int wid = blockIdx.x * 4 + (threadIdx.x >> 6);
    int lane = threadIdx.x & 63;
    int b = wid >> 15;                // N = 32768
    int n = wid & (NN - 1);
    int d = n >> 10, h = (n >> 5) & 31, w = n & 31;

    float qt = theta[((size_t)b * NN + n) * 64 + lane];
    float qg = gth[(size_t)n * 64 + lane];
    const float rs = 0.2294157338705618f;  // 1/sqrt(19)
    float s_mine = -INFINITY;

#pragma unroll
    for (int k = 0; k < KK; ++k) {
        int nd = d + OFF[k][0], nh = h + OFF[k][1], nw = w + OFF[k][2];
        bool valid = ((unsigned)nd < 32u) && ((unsigned)nh < 32u) && ((unsigned)nw < 32u);
        int nn = valid ? ((nd << 10) + (nh << 5) + nw) : n;
        float part = qt * phi[((size_t)b * NN + nn) * 64 + lane]
                   + qg * gph[(size_t)nn * 64 + lane];
#pragma unroll
        for (int off = 32; off; off >>= 1) part += __shfl_xor(part, off, 64);
        float s = valid ? part * rs : -INFINITY;
        if (lane == k) s_mine = s;
    }
    // softmax across lanes 0..18 (lanes >= 19 hold -inf)
    float m = s_mine;
#pragma unroll
    for (int off = 32; off; off >>= 1) m = fmaxf(m, __shfl_xor(m, off, 64));
    float e = (lane < KK) ? __expf(s_mine - m) : 0.f;
    float sum = e;
#pragma unroll
    for (int off = 32; off; off >>= 1) sum += __shfl_xor(sum, off, 64);
    if (lane < KK) wgt[((size_t)b * KK + lane) * NN + n] = e / sum;
}

// ---------------- Kernel 4: one propagation iteration ----------------
// out[b,c,n] = sum_k wgt[b,k,n] * cin[b,c,nbr(n,k)]   (invalid k have wgt==0)
__global__ __launch_bounds__(256) void prop_kernel(
    const float* __restrict__ cin, const float* __restrict__ wgt,
    float* __restrict__ cout)
{
    int gid = blockIdx.x * 256 + threadIdx.x;   // B*CC*N threads
    int n = gid & (NN - 1);
    int bc = gid >> 15;
    int b = bc / CC, c = bc % CC;
    int d = n >> 10, h = (n >> 5) & 31, w = n & 31;
    float acc = 0.f;
    const float* wb = wgt + (size_t)b * KK * NN;
    const float* cb = cin + ((size_t)b * CC + c) * NN;
#pragma unroll
    for (int k = 0; k < KK; ++k) {
        int nd = d + OFF[k][0], nh = h + OFF[k][1], nw = w + OFF[k][2];
        nd = min(max(nd, 0), 31); nh = min(max(nh, 0), 31); nw = min(max(nw, 0), 31);
        int nn = (nd << 10) + (nh << 5) + nw;
        acc += wb[(size_t)k * NN + n] * cb[nn];
    }
    cout[((size_t)b * CC + c) * NN + n] = acc;
}

extern "C" void kernel_launch(void* const* d_in, const int* in_sizes, int n_in,
                              void* d_out, int out_size, void* d_ws, size_t ws_size,
                              hipStream_t stream) {
    const float* cam = (const float*)d_in[0];
    const float* f   = (const float*)d_in[1];
    const float* thw = (const float*)d_in[2];
    const float* thb = (const float*)d_in[3];
    const float* phw = (const float*)d_in[4];
    const float* phb = (const float*)d_in[5];
    const float* gtw = (const float*)d_in[6];
    const float* gtb = (const float*)d_in[7];
    const float* gpw = (const float*)d_in[8];
    const float* gpb = (const float*)d_in[9];

    float* ws    = (float*)d_ws;
    float* theta = ws;                                   // [B,N,64]
    float* phi   = theta + (size_t)BB * NN * 64;         // [B,N,64]
    float* gth   = phi   + (size_t)BB * NN * 64;         // [N,64]
    float* gph   = gth   + (size_t)NN * 64;              // [N,64]
    float* wgt   = gph   + (size_t)NN * 64;              // [B,19,N]
    float* cam1  = wgt   + (size_t)BB * KK * NN;         // [B,21,N]

    proj_kernel<<<512, 256, 0, stream>>>(f, thw, thb, phw, phb, theta, phi);
    geo_kernel<<<NN / 4, 256, 0, stream>>>(gtw, gtb, gpw, gpb, gth, gph);
    score_kernel<<<BB * NN / 4, 256, 0, stream>>>(theta, phi, gth, gph, wgt);
    prop_kernel<<<BB * CC * NN / 256, 256, 0, stream>>>(cam, wgt, cam1);
    prop_kernel<<<BB * CC * NN / 256, 256, 0, stream>>>(cam1, wgt, (float*)d_out);
}

// Round 2
// 186.340 us; speedup vs baseline: 1.0515x; 1.0515x over previous
//
#include <hip/hip_runtime.h>
#include <hip/hip_bf16.h>

#define DD 32
#define HH 32
#define WW 32
#define NN 32768
#define BB 2
#define CF 256
#define CC 21
#define FD 64
#define KK 19
#define BKP 32

// 19 stencil offsets with |dx|+|dy|+|dz| <= 2 (order irrelevant: softmax+sum over k)
__device__ const int OFF[19][3] = {
    {-1,-1, 0}, {-1, 0,-1}, {-1, 0, 0}, {-1, 0, 1}, {-1, 1, 0},
    { 0,-1,-1}, { 0,-1, 0}, { 0,-1, 1}, { 0, 0,-1}, { 0, 0, 0},
    { 0, 0, 1}, { 0, 1,-1}, { 0, 1, 0}, { 0, 1, 1},
    { 1,-1, 0}, { 1, 0,-1}, { 1, 0, 0}, { 1, 0, 1}, { 1, 1, 0}
};

// ---------------- Kernel 1: projection GEMM ----------------
__global__ __launch_bounds__(256) void proj_kernel(
    const float* __restrict__ f,
    const float* __restrict__ thw, const float* __restrict__ thb,
    const float* __restrict__ phw, const float* __restrict__ phb,
    float* __restrict__ theta, float* __restrict__ phi)
{
    __shared__ __align__(16) float As[BKP][128];  // [kk][m]
    __shared__ __align__(16) float Bs[BKP][128];  // [kk][j]
    int blk = blockIdx.x;
    int b = blk >> 8;                 // 256 blocks per batch
    int n0 = (blk & 255) * 128;
    int tid = threadIdx.x;
    int tm = tid >> 4;                // 0..15
    int tj = tid & 15;                // 0..15
    int m0 = tm * 8, j0 = tj * 8;

    float bias[8];
#pragma unroll
    for (int jj = 0; jj < 8; ++jj)
        bias[jj] = (j0 + jj < 64) ? thb[j0 + jj] : phb[j0 + jj - 64];

    float acc[8][8];
#pragma unroll
    for (int r = 0; r < 8; ++r)
#pragma unroll
        for (int jj = 0; jj < 8; ++jj) acc[r][jj] = 0.f;

    const float* fb = f + (size_t)b * CF * NN;
    int lm = (tid & 31) * 4;          // 0..124
    int lk = tid >> 5;                // 0..7

    for (int k0 = 0; k0 < CF; k0 += BKP) {
#pragma unroll
        for (int i = 0; i < 4; ++i) {
            int kk = lk + i * 8;
            float4 av = *(const float4*)(fb + (size_t)(k0 + kk) * NN + n0 + lm);
            *(float4*)&As[kk][lm] = av;
            float4 wv;
            if (lm < 64) wv = *(const float4*)(thw + (k0 + kk) * 64 + lm);
            else         wv = *(const float4*)(phw + (k0 + kk) * 64 + (lm - 64));
            *(float4*)&Bs[kk][lm] = wv;
        }
        __syncthreads();
#pragma unroll
        for (int kk = 0; kk < BKP; ++kk) {
            float a[8], bb[8];
            *(float4*)&a[0]  = *(float4*)&As[kk][m0];
            *(float4*)&a[4]  = *(float4*)&As[kk][m0 + 4];
            *(float4*)&bb[0] = *(float4*)&Bs[kk][j0];
            *(float4*)&bb[4] = *(float4*)&Bs[kk][j0 + 4];
#pragma unroll
            for (int r = 0; r < 8; ++r)
#pragma unroll
                for (int jj = 0; jj < 8; ++jj) acc[r][jj] += a[r] * bb[jj];
        }
        __syncthreads();
    }

#pragma unroll
    for (int r = 0; r < 8; ++r) {
        int n = n0 + m0 + r;
        float out[8];
#pragma unroll
        for (int jj = 0; jj < 8; ++jj) out[jj] = acc[r][jj] + bias[jj];
        if (j0 < 64) {
            *(float4*)(theta + ((size_t)b * NN + n) * 64 + j0)     = *(float4*)&out[0];
            *(float4*)(theta + ((size_t)b * NN + n) * 64 + j0 + 4) = *(float4*)&out[4];
        } else {
            *(float4*)(phi + ((size_t)b * NN + n) * 64 + (j0 - 64))     = *(float4*)&out[0];
            *(float4*)(phi + ((size_t)b * NN + n) * 64 + (j0 - 64) + 4) = *(float4*)&out[4];
        }
    }
}

// ---------------- Kernel 2: geo projection ----------------
__global__ __launch_bounds__(256) void geo_kernel(
    const float* __restrict__ gtw, const float* __restrict__ gtb,
    const float* __restrict__ gpw, const float* __restrict__ gpb,
    float* __restrict__ gth, float* __restrict__ gph)
{
    __shared__ float pe_s[4][48];
    int tid = threadIdx.x;
    int n_base = blockIdx.x * 4;
    if (tid < 192) {
        int node = tid / 48, p = tid % 48;
        int n = n_base + node;
        int d = n >> 10, h = (n >> 5) & 31, w = n & 31;
        int a = p / 16, rem = p % 16, i = rem >> 1, sc = rem & 1;
        float coord = (a == 0) ? (float)d : (a == 1) ? (float)h : (float)w;
        float div = expf(-9.210340371976184f * (float)i * 0.125f);  // (1e-4)^(i/8)
        float ang = coord * div;
        pe_s[node][p] = sc ? cosf(ang) : sinf(ang);
    }
    __syncthreads();
    int node = tid >> 6, j = tid & 63;
    int n = n_base + node;
    float at = gtb[j], ap = gpb[j];
#pragma unroll
    for (int p = 0; p < 48; ++p) {
        float pv = pe_s[node][p];
        at += pv * gtw[p * 64 + j];
        ap += pv * gpw[p * 64 + j];
    }
    gth[(size_t)n * 64 + j] = at;
    gph[(size_t)n * 64 + j] = ap;
}

// ---------------- Kernel 2b: geo scores (batch-independent) ----------------
// gsc[n,k] = rs * (g_theta[n] . g_phi[nbr(n,k)]),  -inf for invalid edges.
// one wave per 3 nodes; lane = node_in_wave*19 + k; serial 64-dim dot, no shuffles.
__global__ __launch_bounds__(256) void geo_score_kernel(
    const float* __restrict__ gth, const float* __restrict__ gph,
    float* __restrict__ gsc)
{
    int wid = blockIdx.x * 4 + (threadIdx.x >> 6);
    int lane = threadIdx.x & 63;
    int node = lane / 19;
    int k = lane - node * 19;
    int n = wid * 3 + node;
    bool active = (node < 3) && (n < NN);
    if (!active) return;

    int d = n >> 10, h = (n >> 5) & 31, w = n & 31;
    int nd = d + OFF[k][0], nh = h + OFF[k][1], nw = w + OFF[k][2];
    bool valid = ((unsigned)nd < 32u) && ((unsigned)nh < 32u) && ((unsigned)nw < 32u);
    int nn = valid ? ((nd << 10) + (nh << 5) + nw) : n;

    const float* tr = gth + (size_t)n * 64;
    const float* pr = gph + (size_t)nn * 64;
    float acc = 0.f;
#pragma unroll
    for (int i = 0; i < 16; ++i) {
        float4 t = *(const float4*)(tr + i * 4);
        float4 p = *(const float4*)(pr + i * 4);
        acc = fmaf(t.x, p.x, acc); acc = fmaf(t.y, p.y, acc);
        acc = fmaf(t.z, p.z, acc); acc = fmaf(t.w, p.w, acc);
    }
    const float rs = 0.2294157338705618f;  // 1/sqrt(19)
    gsc[(size_t)n * KK + k] = valid ? acc * rs : -INFINITY;
}

// ---------------- Kernel 3: scores + masked softmax ----------------
// lane = node_in_wave*19 + k; serial 64-dim theta.phi dot; geo term precomputed.
// softmax over the 19-lane group via two LDS broadcast rounds.
__global__ __launch_bounds__(256) void score_kernel(
    const float* __restrict__ theta, const float* __restrict__ phi,
    const float* __restrict__ gsc, float* __restrict__ wgt)
{
    __shared__ float sbuf[4][3][20];
    __shared__ float ebuf[4][3][20];
    int wv = threadIdx.x >> 6;
    int lane = threadIdx.x & 63;
    int wid = blockIdx.x * 4 + wv;
    int node = lane / 19;
    int k = lane - node * 19;
    int gn = wid * 3 + node;                 // global (b,n) index over B*N
    bool active = (node < 3) && (gn < BB * NN);
    int gnc = active ? gn : (BB * NN - 1);
    int n = gnc & (NN - 1);

    int d = n >> 10, h = (n >> 5) & 31, w = n & 31;
    int nd = d + OFF[k][0], nh = h + OFF[k][1], nw = w + OFF[k][2];
    bool valid = ((unsigned)nd < 32u) && ((unsigned)nh < 32u) && ((unsigned)nw < 32u);
    int nn = valid ? ((nd << 10) + (nh << 5) + nw) : n;

    const float* tr = theta + (size_t)gnc * 64;
    const float* pr = phi + (size_t)(gnc - n + nn) * 64;
    float acc = 0.f;
#pragma unroll
    for (int i = 0; i < 16; ++i) {
        float4 t = *(const float4*)(tr + i * 4);
        float4 p = *(const float4*)(pr + i * 4);
        acc = fmaf(t.x, p.x, acc); acc = fmaf(t.y, p.y, acc);
        acc = fmaf(t.z, p.z, acc); acc = fmaf(t.w, p.w, acc);
    }
    const float rs = 0.2294157338705618f;  // 1/sqrt(19)
    // gsc holds rs*geo_dot, or -inf for invalid edges -> s = -inf there
    float s = fmaf(acc, rs, gsc[(size_t)n * KK + k]);

    if (active) sbuf[wv][node][k] = s;
    __syncthreads();
    float m = -INFINITY;
#pragma unroll
    for (int j = 0; j < KK; ++j) m = fmaxf(m, sbuf[wv][node][j]);
    float e = (active && valid) ? __expf(s - m) : 0.f;
    if (active) ebuf[wv][node][k] = e;
    __syncthreads();
    float sum = 0.f;
#pragma unroll
    for (int j = 0; j < KK; ++j) sum += ebuf[wv][node][j];
    if (active) wgt[((size_t)(gnc >> 15) * KK + k) * NN + n] = e / sum;
}

// ---------------- Kernel 4: one propagation iteration ----------------
__global__ __launch_bounds__(256) void prop_kernel(
    const float* __restrict__ cin, const float* __restrict__ wgt,
    float* __restrict__ cout)
{
    int gid = blockIdx.x * 256 + threadIdx.x;   // B*CC*N threads
    int n = gid & (NN - 1);
    int bc = gid >> 15;
    int b = bc / CC, c = bc % CC;
    int d = n >> 10, h = (n >> 5) & 31, w = n & 31;
    float acc = 0.f;
    const float* wb = wgt + (size_t)b * KK * NN;
    const float* cb = cin + ((size_t)b * CC + c) * NN;
#pragma unroll
    for (int k = 0; k < KK; ++k) {
        int nd = d + OFF[k][0], nh = h + OFF[k][1], nw = w + OFF[k][2];
        nd = min(max(nd, 0), 31); nh = min(max(nh, 0), 31); nw = min(max(nw, 0), 31);
        int nn = (nd << 10) + (nh << 5) + nw;
        acc += wb[(size_t)k * NN + n] * cb[nn];
    }
    cout[((size_t)b * CC + c) * NN + n] = acc;
}

extern "C" void kernel_launch(void* const* d_in, const int* in_sizes, int n_in,
                              void* d_out, int out_size, void* d_ws, size_t ws_size,
                              hipStream_t stream) {
    const float* cam = (const float*)d_in[0];
    const float* f   = (const float*)d_in[1];
    const float* thw = (const float*)d_in[2];
    const float* thb = (const float*)d_in[3];
    const float* phw = (const float*)d_in[4];
    const float* phb = (const float*)d_in[5];
    const float* gtw = (const float*)d_in[6];
    const float* gtb = (const float*)d_in[7];
    const float* gpw = (const float*)d_in[8];
    const float* gpb = (const float*)d_in[9];

    float* ws    = (float*)d_ws;
    float* theta = ws;                                   // [B,N,64]
    float* phi   = theta + (size_t)BB * NN * 64;         // [B,N,64]
    float* gth   = phi   + (size_t)BB * NN * 64;         // [N,64]
    float* gph   = gth   + (size_t)NN * 64;              // [N,64]
    float* wgt   = gph   + (size_t)NN * 64;              // [B,19,N]
    float* cam1  = wgt   + (size_t)BB * KK * NN;         // [B,21,N]
    float* gsc   = cam1;                                 // [N,19] aliases cam1:
    // gsc written by geo_score, read only by score_kernel; cam1 written by
    // prop_kernel strictly after score_kernel on the same stream.

    proj_kernel<<<512, 256, 0, stream>>>(f, thw, thb, phw, phb, theta, phi);
    geo_kernel<<<NN / 4, 256, 0, stream>>>(gtw, gtb, gpw, gpb, gth, gph);
    {
        int waves = (NN + 2) / 3;
        int blocks = (waves + 3) / 4;
        geo_score_kernel<<<blocks, 256, 0, stream>>>(gth, gph, gsc);
    }
    {
        int waves = (BB * NN + 2) / 3;
        int blocks = (waves + 3) / 4;
        score_kernel<<<blocks, 256, 0, stream>>>(theta, phi, gsc, wgt);
    }
    prop_kernel<<<BB * CC * NN / 256, 256, 0, stream>>>(cam, wgt, cam1);
    prop_kernel<<<BB * CC * NN / 256, 256, 0, stream>>>(cam1, wgt, (float*)d_out);
}